// Round 1
// baseline (88.547 us; speedup 1.0000x reference)
//
#include <hip/hip_runtime.h>

// GeodesicConv: out[p,d] = sum_c feat[p,c] * filters[bin(p)][c][d] + bias[d]
// bin(p) = ring(radial)*8 + orient(angular), 40 bins of 32x32 f32 matrices.
//
// Layout: 256-thread blocks, 64 points/block (grid 2048). Each wave handles
// 16 points, 2 per iteration (half-wave per point, lane = output channel d).
// Features staged in LDS (float4 broadcast reads, 2-addr/wave = free 2-way),
// W rows gathered from global: 32 lanes x 4B consecutive = 128B coalesced row,
// L2-resident (filters = 160 KB total).
//
// Bin math must be bit-identical to numpy f32: mul, IEEE div, trunc-to-int.
// No fast-math; (a*8.0f)/TWO_PI_F stays an IEEE f32 divide at -O3.

#define NPTS_PER_BLOCK 64
#define THREADS 256

__global__ __launch_bounds__(THREADS, 4)
void geodesic_conv_kernel(const float* __restrict__ feat,
                          const float* __restrict__ coords,
                          const float* __restrict__ filt,
                          const float* __restrict__ bias,
                          float* __restrict__ out)
{
    __shared__ float4 lds_f4[NPTS_PER_BLOCK * 8];   // 64 pts x 32 f32 = 8 KB
    __shared__ int    lds_bin[NPTS_PER_BLOCK];

    const int tid   = threadIdx.x;
    const int pbase = blockIdx.x * NPTS_PER_BLOCK;

    // Stage features: 64 pts * 128 B = 8 KB, contiguous, coalesced float4.
    const float4* gf4 = reinterpret_cast<const float4*>(feat) + (size_t)pbase * 8;
    lds_f4[tid]       = gf4[tid];
    lds_f4[tid + 256] = gf4[tid + 256];

    // Bins for the block's 64 points (threads 0..63, float2 coalesced).
    if (tid < NPTS_PER_BLOCK) {
        float2 rc = reinterpret_cast<const float2*>(coords)[pbase + tid];
        int ri = (int)(rc.x * 5.0f);              // trunc, matches astype(int32)
        ri = min(max(ri, 0), 4);
        const float TWO_PI_F = (float)(2.0 * 3.14159);
        int oi = (int)((rc.y * 8.0f) / TWO_PI_F); // IEEE f32 div, then trunc
        oi = min(max(oi, 0), 7);
        lds_bin[tid] = ri * 8 + oi;
    }
    __syncthreads();

    const int wave = tid >> 6;       // 0..3
    const int lane = tid & 63;
    const int half = lane >> 5;      // which of the 2 points this iteration
    const int d    = lane & 31;      // output channel
    const float bs = bias[d];

    for (int i = 0; i < 8; ++i) {
        const int p   = wave * 16 + i * 2 + half;
        const int bin = lds_bin[p];
        // W row gather: 32 lanes read W[bin][c][d], d contiguous -> 128 B/row.
        const float* W = filt + (size_t)bin * 1024 + d;
        float acc = 0.0f;
        #pragma unroll
        for (int c4 = 0; c4 < 8; ++c4) {
            float4 fv = lds_f4[p * 8 + c4];       // broadcast within half-wave
            acc += fv.x * W[(c4 * 4 + 0) * 32];   // imm offsets c*128 <= 3968
            acc += fv.y * W[(c4 * 4 + 1) * 32];
            acc += fv.z * W[(c4 * 4 + 2) * 32];
            acc += fv.w * W[(c4 * 4 + 3) * 32];
        }
        // lanes 0..63 write 2 consecutive points' 32 floats = 256 B contiguous
        out[(size_t)(pbase + p) * 32 + d] = acc + bs;
    }
}

extern "C" void kernel_launch(void* const* d_in, const int* in_sizes, int n_in,
                              void* d_out, int out_size, void* d_ws, size_t ws_size,
                              hipStream_t stream) {
    const float* feat   = (const float*)d_in[0];
    const float* coords = (const float*)d_in[1];
    const float* filt   = (const float*)d_in[2];
    const float* bias   = (const float*)d_in[3];
    float* out = (float*)d_out;

    const int npts    = in_sizes[0] / 32;            // B*N = 131072
    const int nblocks = npts / NPTS_PER_BLOCK;       // 2048
    geodesic_conv_kernel<<<nblocks, THREADS, 0, stream>>>(feat, coords, filt, bias, out);
}